// Round 1
// baseline (458.210 us; speedup 1.0000x reference)
//
#include <hip/hip_runtime.h>
#include <hip/hip_bf16.h>

typedef unsigned short u16;
typedef unsigned int u32;

#define N_ 256
#define C_ 128
#define H_ 4
#define DH_ 32
#define R_ (N_*N_)

static constexpr float KEY_SCALE_ = 0.17677669529663687f; // 32^-0.5

__device__ __forceinline__ float bf2f(u16 b){ return __uint_as_float(((u32)b)<<16); }
__device__ __forceinline__ u16 f2bf(float f){
  u32 u = __float_as_uint(f);
  u += 0x7FFFu + ((u>>16)&1u);   // round-to-nearest-even
  return (u16)(u>>16);
}

// ---------------- fused input projections: q (scaled), k, v, gate ----------
// grid = R_/32, block = 256. Threads 0..127: wq+wg on q_data; 128..255: wk+wv on m_data.
__global__ __launch_bounds__(256) void proj_kernel(
    const float* __restrict__ qd, const float* __restrict__ md,
    const float* __restrict__ wq, const float* __restrict__ wk,
    const float* __restrict__ wv, const float* __restrict__ wg,
    const float* __restrict__ bg,
    u16* __restrict__ qb, u16* __restrict__ kb,
    u16* __restrict__ vb, u16* __restrict__ gb)
{
  __shared__ float xq[32*C_];
  __shared__ float xm[32*C_];
  const int t = threadIdx.x;
  const int col = t & 127;
  const int grp = t >> 7;
  const size_t row0 = (size_t)blockIdx.x * 32;

  {
    const float4* q4 = (const float4*)(qd + row0*C_);
    const float4* m4 = (const float4*)(md + row0*C_);
    float4* xq4 = (float4*)xq;
    float4* xm4 = (float4*)xm;
    #pragma unroll
    for (int p=0;p<4;p++){ int i = t + p*256; xq4[i]=q4[i]; xm4[i]=m4[i]; }
  }
  __syncthreads();

  const float* W1 = grp ? wk : wq;
  const float* W2 = grp ? wv : wg;
  const float* X  = grp ? xm : xq;

  float acc1[32], acc2[32];
  #pragma unroll
  for (int r=0;r<32;r++){ acc1[r]=0.f; acc2[r]=0.f; }

  const float* w1p = W1 + col*C_;
  const float* w2p = W2 + col*C_;
  #pragma unroll 2
  for (int c0=0;c0<C_;c0+=4){
    const float4 w1 = *(const float4*)(w1p + c0);
    const float4 w2 = *(const float4*)(w2p + c0);
    #pragma unroll
    for (int r=0;r<32;r++){
      const float4 xv = *(const float4*)(X + r*C_ + c0);
      acc1[r] += xv.x*w1.x + xv.y*w1.y + xv.z*w1.z + xv.w*w1.w;
      acc2[r] += xv.x*w2.x + xv.y*w2.y + xv.z*w2.z + xv.w*w2.w;
    }
  }

  if (grp==0){
    const float bgv = bg[col];
    #pragma unroll
    for (int r=0;r<32;r++){
      size_t idx = (row0+r)*C_ + col;
      qb[idx] = f2bf(acc1[r]*KEY_SCALE_);
      gb[idx] = f2bf(1.f/(1.f+__expf(-(acc2[r]+bgv))));
    }
  } else {
    #pragma unroll
    for (int r=0;r<32;r++){
      size_t idx = (row0+r)*C_ + col;
      kb[idx] = f2bf(acc1[r]);
      vb[idx] = f2bf(acc2[r]);
    }
  }
}

// ---------------- attention: one block per (n, h) --------------------------
// block = 256 threads = 4 waves; each wave owns 8 q-rows per pass, 8 passes.
// K/V in LDS bf16 with 36-elem (72B) padded rows -> conflict-free b64 reads.
#define KSTR 36
__global__ __launch_bounds__(256) void attn_kernel(
    const u16* __restrict__ qb, const u16* __restrict__ kb,
    const u16* __restrict__ vb, const u16* __restrict__ gb,
    const float* __restrict__ bias, const float* __restrict__ nbias,
    u16* __restrict__ wab)
{
  __shared__ u16 Ks[256*KSTR];      // 18432 B
  __shared__ u16 Vs[256*KSTR];      // 18432 B
  __shared__ float Ws[4][256*9];    // 36864 B (per-wave softmax weights, [k][r])
  __shared__ float Bs[256];         // 1024 B
  __shared__ float Qs[32*36];       // 4608 B   => total 79360 B (2 blocks/CU)

  const int t = threadIdx.x;
  const int h = blockIdx.x;
  const int n = blockIdx.y;
  const int l = t & 63;
  const int wv_ = t >> 6;

  // stage K, V (256 x 32 bf16 each), bias row
  {
    const u16* ksrc = kb + ((size_t)n*N_)*C_ + h*DH_;
    const u16* vsrc = vb + ((size_t)n*N_)*C_ + h*DH_;
    for (int id = t; id < 2048; id += 256){
      int k = id >> 3, c = id & 7;
      ushort4 kvv = *(const ushort4*)(ksrc + (size_t)k*C_ + c*4);
      ushort4 vvv = *(const ushort4*)(vsrc + (size_t)k*C_ + c*4);
      *(ushort4*)&Ks[k*KSTR + c*4] = kvv;
      *(ushort4*)&Vs[k*KSTR + c*4] = vvv;
    }
    Bs[t & 255] = bias[(size_t)n*N_ + (t & 255)];
  }

  const float* nbp = nbias + (size_t)h*N_*N_;

  for (int q0 = 0; q0 < N_; q0 += 32){
    __syncthreads();   // staging done / previous pass's Qs reads done
    {
      int r = t >> 3, c = t & 7;
      const u16* qsrc = qb + ((size_t)(n*N_ + q0 + r))*C_ + h*DH_ + c*4;
      ushort4 qv = *(const ushort4*)qsrc;
      float4 qf;
      qf.x = bf2f(qv.x); qf.y = bf2f(qv.y); qf.z = bf2f(qv.z); qf.w = bf2f(qv.w);
      *(float4*)&Qs[r*36 + c*4] = qf;
    }
    __syncthreads();

    const int qr0 = q0 + wv_*8;

    // logits init with biases: lane l owns k = l + 64j
    float lg[8][4];
    float bv[4];
    #pragma unroll
    for (int j=0;j<4;j++) bv[j] = Bs[l + 64*j];
    #pragma unroll
    for (int r=0;r<8;r++){
      #pragma unroll
      for (int j=0;j<4;j++)
        lg[r][j] = bv[j] + nbp[(size_t)(qr0+r)*N_ + l + 64*j];
    }

    // QK^T over d-chunks of 4
    #pragma unroll
    for (int c=0;c<8;c++){
      float kf[4][4];
      #pragma unroll
      for (int j=0;j<4;j++){
        uint2 kvv = *(const uint2*)&Ks[(l+64*j)*KSTR + c*4];
        kf[j][0] = __uint_as_float(kvv.x<<16);
        kf[j][1] = __uint_as_float(kvv.x & 0xFFFF0000u);
        kf[j][2] = __uint_as_float(kvv.y<<16);
        kf[j][3] = __uint_as_float(kvv.y & 0xFFFF0000u);
      }
      #pragma unroll
      for (int r=0;r<8;r++){
        const float4 qv = *(const float4*)&Qs[(wv_*8+r)*36 + c*4];
        #pragma unroll
        for (int j=0;j<4;j++)
          lg[r][j] += qv.x*kf[j][0] + qv.y*kf[j][1] + qv.z*kf[j][2] + qv.w*kf[j][3];
      }
    }

    // wave-parallel softmax over 256 k (lanes x 4)
    float invs[8];
    float* wbuf = &Ws[wv_][0];
    #pragma unroll
    for (int r=0;r<8;r++){
      float m = fmaxf(fmaxf(lg[r][0],lg[r][1]), fmaxf(lg[r][2],lg[r][3]));
      #pragma unroll
      for (int s=32;s>=1;s>>=1) m = fmaxf(m, __shfl_xor(m, s));
      float p[4], sum = 0.f;
      #pragma unroll
      for (int j=0;j<4;j++){ p[j] = __expf(lg[r][j]-m); sum += p[j]; }
      #pragma unroll
      for (int s=32;s>=1;s>>=1) sum += __shfl_xor(sum, s);
      invs[r] = 1.f/sum;
      #pragma unroll
      for (int j=0;j<4;j++) wbuf[(l+64*j)*9 + r] = p[j];
    }

    // PV: lane l -> d = l&31, k-half = l>>5
    float acc[8];
    #pragma unroll
    for (int r=0;r<8;r++) acc[r]=0.f;
    const int d = l & 31;
    const int kh = (l>>5)*128;
    #pragma unroll 4
    for (int kk=0; kk<128; kk++){
      int k = kh + kk;
      float vvf = bf2f(Vs[k*KSTR + d]);
      #pragma unroll
      for (int r=0;r<8;r++) acc[r] += wbuf[k*9+r] * vvf;
    }
    #pragma unroll
    for (int r=0;r<8;r++) acc[r] += __shfl_xor(acc[r], 32);

    // gate + store (lower half stores rows 0..3, upper 4..7)
    const int rbase = (l<32) ? 0 : 4;
    #pragma unroll
    for (int i=0;i<4;i++){
      int r = rbase + i;
      size_t row = (size_t)n*N_ + qr0 + r;
      float gv = bf2f(gb[row*C_ + h*DH_ + d]);
      wab[row*C_ + h*DH_ + d] = f2bf(acc[r]*invs[r]*gv);
    }
  }
}

// ---------------- output projection ----------------------------------------
__global__ __launch_bounds__(128) void outproj_kernel(
    const u16* __restrict__ wab, const float* __restrict__ wo,
    const float* __restrict__ bo, float* __restrict__ out)
{
  __shared__ float xf[32*C_];
  const int t = threadIdx.x;
  const size_t row0 = (size_t)blockIdx.x * 32;
  {
    const u16* src = wab + row0*C_;
    #pragma unroll
    for (int p=0;p<8;p++){
      int id = t + p*128;
      ushort4 xv = *(const ushort4*)(src + id*4);
      float4 xf4;
      xf4.x = bf2f(xv.x); xf4.y = bf2f(xv.y); xf4.z = bf2f(xv.z); xf4.w = bf2f(xv.w);
      ((float4*)xf)[id] = xf4;
    }
  }
  __syncthreads();
  float acc[32];
  #pragma unroll
  for (int r=0;r<32;r++) acc[r]=0.f;
  const float* wp = wo + t*C_;
  #pragma unroll 2
  for (int c0=0;c0<C_;c0+=4){
    const float4 w4 = *(const float4*)(wp + c0);
    #pragma unroll
    for (int r=0;r<32;r++){
      const float4 xv = *(const float4*)&xf[r*C_ + c0];
      acc[r] += xv.x*w4.x + xv.y*w4.y + xv.z*w4.z + xv.w*w4.w;
    }
  }
  const float bov = bo[t];
  #pragma unroll
  for (int r=0;r<32;r++)
    out[(row0+r)*C_ + t] = acc[r] + bov;
}

extern "C" void kernel_launch(void* const* d_in, const int* in_sizes, int n_in,
                              void* d_out, int out_size, void* d_ws, size_t ws_size,
                              hipStream_t stream) {
  const float* qd   = (const float*)d_in[0];
  const float* md   = (const float*)d_in[1];
  const float* bias = (const float*)d_in[2];
  const float* nb   = (const float*)d_in[3];
  const float* wq   = (const float*)d_in[4];
  const float* wk   = (const float*)d_in[5];
  const float* wv   = (const float*)d_in[6];
  const float* wo   = (const float*)d_in[7];
  const float* bo   = (const float*)d_in[8];
  const float* wg   = (const float*)d_in[9];
  const float* bg   = (const float*)d_in[10];
  float* out = (float*)d_out;

  char* ws = (char*)d_ws;
  const size_t MB16 = (size_t)16*1024*1024;
  u16* qb  = (u16*)(ws);            // q projection; reused in-place for wa*g
  u16* kb  = (u16*)(ws + MB16);
  u16* vb  = (u16*)(ws + 2*MB16);
  u16* gb  = (u16*)(ws + 3*MB16);
  u16* wab = qb;                    // safe in-place reuse (disjoint row/col slices)

  proj_kernel<<<R_/32, 256, 0, stream>>>(qd, md, wq, wk, wv, wg, bg, qb, kb, vb, gb);
  attn_kernel<<<dim3(H_, N_), 256, 0, stream>>>(qb, kb, vb, gb, bias, nb, wab);
  outproj_kernel<<<R_/32, 128, 0, stream>>>(wab, wo, bo, out);
}

// Round 2
// 292.703 us; speedup vs baseline: 1.5654x; 1.5654x over previous
//
#include <hip/hip_runtime.h>
#include <hip/hip_bf16.h>

typedef unsigned short u16;
typedef unsigned int u32;

#define N_ 256
#define C_ 128
#define H_ 4
#define DH_ 32
#define R_ (N_*N_)

static constexpr float KEY_SCALE_ = 0.17677669529663687f; // 32^-0.5

typedef __attribute__((ext_vector_type(8))) short bf16x8;
typedef __attribute__((ext_vector_type(4))) float f32x4;

__device__ __forceinline__ float bf2f(u16 b){ return __uint_as_float(((u32)b)<<16); }
__device__ __forceinline__ u16 f2bf(float f){
  u32 u = __float_as_uint(f);
  u += 0x7FFFu + ((u>>16)&1u);   // round-to-nearest-even
  return (u16)(u>>16);
}

// ---------------- fused input projections: q (scaled), k, v, gate ----------
// grid = R_/32, block = 256. Threads 0..127: wq+wg on q_data; 128..255: wk+wv on m_data.
__global__ __launch_bounds__(256) void proj_kernel(
    const float* __restrict__ qd, const float* __restrict__ md,
    const float* __restrict__ wq, const float* __restrict__ wk,
    const float* __restrict__ wv, const float* __restrict__ wg,
    const float* __restrict__ bg,
    u16* __restrict__ qb, u16* __restrict__ kb,
    u16* __restrict__ vb, u16* __restrict__ gb)
{
  __shared__ float xq[32*C_];
  __shared__ float xm[32*C_];
  const int t = threadIdx.x;
  const int col = t & 127;
  const int grp = t >> 7;
  const size_t row0 = (size_t)blockIdx.x * 32;

  {
    const float4* q4 = (const float4*)(qd + row0*C_);
    const float4* m4 = (const float4*)(md + row0*C_);
    float4* xq4 = (float4*)xq;
    float4* xm4 = (float4*)xm;
    #pragma unroll
    for (int p=0;p<4;p++){ int i = t + p*256; xq4[i]=q4[i]; xm4[i]=m4[i]; }
  }
  __syncthreads();

  const float* W1 = grp ? wk : wq;
  const float* W2 = grp ? wv : wg;
  const float* X  = grp ? xm : xq;

  float acc1[32], acc2[32];
  #pragma unroll
  for (int r=0;r<32;r++){ acc1[r]=0.f; acc2[r]=0.f; }

  const float* w1p = W1 + col*C_;
  const float* w2p = W2 + col*C_;
  #pragma unroll 2
  for (int c0=0;c0<C_;c0+=4){
    const float4 w1 = *(const float4*)(w1p + c0);
    const float4 w2 = *(const float4*)(w2p + c0);
    #pragma unroll
    for (int r=0;r<32;r++){
      const float4 xv = *(const float4*)(X + r*C_ + c0);
      acc1[r] += xv.x*w1.x + xv.y*w1.y + xv.z*w1.z + xv.w*w1.w;
      acc2[r] += xv.x*w2.x + xv.y*w2.y + xv.z*w2.z + xv.w*w2.w;
    }
  }

  if (grp==0){
    const float bgv = bg[col];
    #pragma unroll
    for (int r=0;r<32;r++){
      size_t idx = (row0+r)*C_ + col;
      qb[idx] = f2bf(acc1[r]*KEY_SCALE_);
      gb[idx] = f2bf(1.f/(1.f+__expf(-(acc2[r]+bgv))));
    }
  } else {
    #pragma unroll
    for (int r=0;r<32;r++){
      size_t idx = (row0+r)*C_ + col;
      kb[idx] = f2bf(acc1[r]);
      vb[idx] = f2bf(acc2[r]);
    }
  }
}

// ---------------- attention (MFMA): one block per (n, h) -------------------
// 4 waves; wave w owns q-rows [64w, 64w+64), processed as 4 q-tiles of 16.
// QK^T: A = Q-frag (global), B = K-frag (global, hoisted in regs, 16 tiles).
// C-operand preloaded with bias + nonbatched_bias. Softmax in C/D layout.
// P -> per-wave LDS (bf16, stride 264), PV: A = P-frag, B = V^T-frag (LDS).
#define VSTR 264
__global__ __launch_bounds__(256) void attn_kernel(
    const u16* qb, const u16* __restrict__ kb,
    const u16* __restrict__ vb, const u16* __restrict__ gb,
    const float* __restrict__ bias, const float* __restrict__ nbias,
    u16* wab)
{
  __shared__ u16 Vt[32*VSTR];        // V transposed: Vt[d][k], 16896 B
  __shared__ u16 Ps[4][16][VSTR];    // per-wave P tile, 33792 B
  __shared__ float Bs[256];          // bias row, 1024 B

  const int t  = threadIdx.x;
  const int h  = blockIdx.x;
  const int n  = blockIdx.y;
  const int w  = t >> 6;
  const int l  = t & 63;
  const int c  = l & 15;       // MFMA "col" lane index
  const int g  = l >> 4;       // MFMA lane group

  // ---- stage V^T (256 k x 32 d) and bias row ----
  {
    const u16* vsrc = vb + ((size_t)n*N_)*C_ + h*DH_;
    for (int id = t; id < 1024; id += 256){
      int k = id >> 2, ch = id & 3;            // 8 d's per chunk
      ushort4 a = *(const ushort4*)(vsrc + (size_t)k*C_ + ch*8);
      ushort4 b = *(const ushort4*)(vsrc + (size_t)k*C_ + ch*8 + 4);
      int d0 = ch*8;
      Vt[(d0+0)*VSTR + k] = a.x;  Vt[(d0+1)*VSTR + k] = a.y;
      Vt[(d0+2)*VSTR + k] = a.z;  Vt[(d0+3)*VSTR + k] = a.w;
      Vt[(d0+4)*VSTR + k] = b.x;  Vt[(d0+5)*VSTR + k] = b.y;
      Vt[(d0+6)*VSTR + k] = b.z;  Vt[(d0+7)*VSTR + k] = b.w;
    }
    Bs[t] = bias[(size_t)n*N_ + t];
  }
  __syncthreads();

  // ---- hoist K B-frags: kf[kt] = K[16kt + c][8g .. 8g+7] ----
  bf16x8 kf[16];
  {
    const u16* kbase = kb + ((size_t)(n*N_ + c))*C_ + h*DH_ + g*8;
    #pragma unroll
    for (int kt=0;kt<16;kt++)
      kf[kt] = *(const bf16x8*)(kbase + (size_t)kt*16*C_);
  }

  const float* nbp = nbias + (size_t)h*N_*N_;

  for (int qt=0; qt<4; qt++){
    const int q0 = w*64 + qt*16;

    // Q A-frag: Q[q0 + c][8g .. 8g+7]
    bf16x8 af = *(const bf16x8*)(qb + ((size_t)(n*N_ + q0 + c))*C_ + h*DH_ + g*8);

    // QK^T with bias preloaded into C
    const float* nbrow = nbp + (size_t)(q0 + 4*g)*N_ + c;
    f32x4 acc[16];
    #pragma unroll
    for (int kt=0;kt<16;kt++){
      const float bsv = Bs[kt*16 + c];
      f32x4 ci;
      #pragma unroll
      for (int r=0;r<4;r++) ci[r] = bsv + nbrow[(size_t)r*N_ + kt*16];
      acc[kt] = __builtin_amdgcn_mfma_f32_16x16x32_bf16(af, kf[kt], ci, 0, 0, 0);
    }

    // softmax across k (16 tiles in regs x 16 lanes of the group)
    float inv[4];
    #pragma unroll
    for (int r=0;r<4;r++){
      float m = acc[0][r];
      #pragma unroll
      for (int kt=1;kt<16;kt++) m = fmaxf(m, acc[kt][r]);
      #pragma unroll
      for (int s=8;s>=1;s>>=1) m = fmaxf(m, __shfl_xor(m, s));
      float sum = 0.f;
      #pragma unroll
      for (int kt=0;kt<16;kt++){
        float p = __expf(acc[kt][r] - m);
        acc[kt][r] = p;
        sum += p;
      }
      #pragma unroll
      for (int s=8;s>=1;s>>=1) sum += __shfl_xor(sum, s);
      inv[r] = 1.f/sum;
    }

    // write P (unnormalized) as bf16 to per-wave LDS
    #pragma unroll
    for (int kt=0;kt<16;kt++){
      #pragma unroll
      for (int r=0;r<4;r++)
        Ps[w][4*g + r][kt*16 + c] = f2bf(acc[kt][r]);
    }

    // PV: out[q][d], d-tiles nd=0,1; K-dim = 256 in 8 steps of 32
    f32x4 o0 = {0.f,0.f,0.f,0.f}, o1 = {0.f,0.f,0.f,0.f};
    #pragma unroll
    for (int s=0;s<8;s++){
      bf16x8 pa = *(const bf16x8*)&Ps[w][c][s*32 + g*8];
      bf16x8 v0 = *(const bf16x8*)&Vt[(size_t)c*VSTR      + s*32 + g*8];
      bf16x8 v1 = *(const bf16x8*)&Vt[(size_t)(16+c)*VSTR + s*32 + g*8];
      o0 = __builtin_amdgcn_mfma_f32_16x16x32_bf16(pa, v0, o0, 0, 0, 0);
      o1 = __builtin_amdgcn_mfma_f32_16x16x32_bf16(pa, v1, o1, 0, 0, 0);
    }

    // normalize, gate, store
    #pragma unroll
    for (int r=0;r<4;r++){
      size_t row = (size_t)n*N_ + q0 + 4*g + r;
      float gv0 = bf2f(gb[row*C_ + h*DH_ + c]);
      float gv1 = bf2f(gb[row*C_ + h*DH_ + 16 + c]);
      wab[row*C_ + h*DH_ + c]      = f2bf(o0[r]*inv[r]*gv0);
      wab[row*C_ + h*DH_ + 16 + c] = f2bf(o1[r]*inv[r]*gv1);
    }
  }
}

// ---------------- output projection ----------------------------------------
__global__ __launch_bounds__(128) void outproj_kernel(
    const u16* __restrict__ wab, const float* __restrict__ wo,
    const float* __restrict__ bo, float* __restrict__ out)
{
  __shared__ float xf[32*C_];
  const int t = threadIdx.x;
  const size_t row0 = (size_t)blockIdx.x * 32;
  {
    const u16* src = wab + row0*C_;
    #pragma unroll
    for (int p=0;p<8;p++){
      int id = t + p*128;
      ushort4 xv = *(const ushort4*)(src + id*4);
      float4 xf4;
      xf4.x = bf2f(xv.x); xf4.y = bf2f(xv.y); xf4.z = bf2f(xv.z); xf4.w = bf2f(xv.w);
      ((float4*)xf)[id] = xf4;
    }
  }
  __syncthreads();
  float acc[32];
  #pragma unroll
  for (int r=0;r<32;r++) acc[r]=0.f;
  const float* wp = wo + t*C_;
  #pragma unroll 2
  for (int c0=0;c0<C_;c0+=4){
    const float4 w4 = *(const float4*)(wp + c0);
    #pragma unroll
    for (int r=0;r<32;r++){
      const float4 xv = *(const float4*)&xf[r*C_ + c0];
      acc[r] += xv.x*w4.x + xv.y*w4.y + xv.z*w4.z + xv.w*w4.w;
    }
  }
  const float bov = bo[t];
  #pragma unroll
  for (int r=0;r<32;r++)
    out[(row0+r)*C_ + t] = acc[r] + bov;
}

extern "C" void kernel_launch(void* const* d_in, const int* in_sizes, int n_in,
                              void* d_out, int out_size, void* d_ws, size_t ws_size,
                              hipStream_t stream) {
  const float* qd   = (const float*)d_in[0];
  const float* md   = (const float*)d_in[1];
  const float* bias = (const float*)d_in[2];
  const float* nb   = (const float*)d_in[3];
  const float* wq   = (const float*)d_in[4];
  const float* wk   = (const float*)d_in[5];
  const float* wv   = (const float*)d_in[6];
  const float* wo   = (const float*)d_in[7];
  const float* bo   = (const float*)d_in[8];
  const float* wg   = (const float*)d_in[9];
  const float* bg   = (const float*)d_in[10];
  float* out = (float*)d_out;

  char* ws = (char*)d_ws;
  const size_t MB16 = (size_t)16*1024*1024;
  u16* qb  = (u16*)(ws);            // q projection; reused in-place for wa*g
  u16* kb  = (u16*)(ws + MB16);
  u16* vb  = (u16*)(ws + 2*MB16);
  u16* gb  = (u16*)(ws + 3*MB16);
  u16* wab = qb;                    // safe in-place reuse (disjoint row/col slices)

  proj_kernel<<<R_/32, 256, 0, stream>>>(qd, md, wq, wk, wv, wg, bg, qb, kb, vb, gb);
  attn_kernel<<<dim3(H_, N_), 256, 0, stream>>>(qb, kb, vb, gb, bias, nb, wab);
  outproj_kernel<<<R_/32, 128, 0, stream>>>(wab, wo, bo, out);
}

// Round 3
// 120.847 us; speedup vs baseline: 3.7917x; 2.4221x over previous
//
#include <hip/hip_runtime.h>
#include <hip/hip_bf16.h>

typedef unsigned short u16;
typedef unsigned int u32;

#define N_ 256
#define C_ 128
#define H_ 4
#define DH_ 32
#define R_ (N_*N_)

static constexpr float KEY_SCALE_ = 0.17677669529663687f; // 32^-0.5

typedef __attribute__((ext_vector_type(8))) short bf16x8;
typedef __attribute__((ext_vector_type(4))) float f32x4;

__device__ __forceinline__ float bf2f(u16 b){ return __uint_as_float(((u32)b)<<16); }
__device__ __forceinline__ u16 f2bf(float f){
  u32 u = __float_as_uint(f);
  u += 0x7FFFu + ((u>>16)&1u);   // round-to-nearest-even
  return (u16)(u>>16);
}

// ---------------- weight pre-conversion: f32 -> bf16 (KEY_SCALE folded) ----
__global__ __launch_bounds__(256) void wconv_kernel(
    const float* __restrict__ wq, const float* __restrict__ wk,
    const float* __restrict__ wv, const float* __restrict__ wg,
    u16* __restrict__ wtb)
{
  int id = blockIdx.x*256 + threadIdx.x;     // 16384 ids x 4 elems
  int m = id >> 12;
  int e = (id & 4095)*4;
  const float* src = (m==0) ? wq : (m==1) ? wk : (m==2) ? wv : wg;
  const float4 v = *(const float4*)(src + e);
  const float s = (m==0) ? KEY_SCALE_ : 1.f;
  ushort4 o;
  o.x = f2bf(v.x*s); o.y = f2bf(v.y*s); o.z = f2bf(v.z*s); o.w = f2bf(v.w*s);
  *(ushort4*)(wtb + m*16384 + e) = o;
}

// ---------------- fused input projections (MFMA) ---------------------------
// grid (256, 2): y=0 -> {wq(scaled), wg} on q_data; y=1 -> {wk, wv} on m_data.
// Block: 256 rows of X staged bf16 in LDS; 4 waves = 2 matrices x 2 col-halves.
#define XSTR 136
__global__ __launch_bounds__(256, 2) void proj_kernel(
    const float* __restrict__ qd, const float* __restrict__ md,
    const u16* __restrict__ wtb, const float* __restrict__ bg,
    u16* __restrict__ qb, u16* __restrict__ kb,
    u16* __restrict__ vb, u16* __restrict__ gb)
{
  __shared__ u16 Xs[256*XSTR];   // 69632 B
  const int t = threadIdx.x;
  const int y = blockIdx.y;
  const size_t row0 = (size_t)blockIdx.x * 256;
  const float* X = y ? md : qd;

  // stage X -> bf16 LDS (each thread 16 chunks of 8)
  #pragma unroll
  for (int p=0;p<16;p++){
    int id = t + p*256;
    int r = id >> 4, c0 = (id & 15)*8;
    const float* s = X + (row0 + r)*C_ + c0;
    float4 a = *(const float4*)s;
    float4 b = *(const float4*)(s+4);
    u16* d = &Xs[r*XSTR + c0];
    d[0]=f2bf(a.x); d[1]=f2bf(a.y); d[2]=f2bf(a.z); d[3]=f2bf(a.w);
    d[4]=f2bf(b.x); d[5]=f2bf(b.y); d[6]=f2bf(b.z); d[7]=f2bf(b.w);
  }

  const int w = t >> 6, l = t & 63, c = l & 15, g = l >> 4;
  const int matSel = w >> 1;            // 0: first matrix, 1: second
  const int ctBase = (w & 1) * 4;       // col-tile half
  const int matIdx = y ? (matSel ? 2 : 1) : (matSel ? 3 : 0);
  u16* dst = y ? (matSel ? vb : kb) : (matSel ? gb : qb);
  const bool doSig = (!y) && matSel;    // gate wave: sigmoid(x + bg)

  // hoist B-frags (weights bf16, from d_out scratch)
  bf16x8 bfr[4][4];
  {
    const u16* wb = wtb + matIdx*16384;
    #pragma unroll
    for (int ctj=0;ctj<4;ctj++){
      const u16* rp = wb + ((ctBase+ctj)*16 + c)*C_ + g*8;
      #pragma unroll
      for (int kk=0;kk<4;kk++)
        bfr[ctj][kk] = *(const bf16x8*)(rp + kk*32);
    }
  }
  float bgv[4];
  if (doSig){
    #pragma unroll
    for (int ctj=0;ctj<4;ctj++) bgv[ctj] = bg[(ctBase+ctj)*16 + c];
  }
  __syncthreads();

  for (int mt=0; mt<16; mt++){
    bf16x8 af[4];
    #pragma unroll
    for (int kk=0;kk<4;kk++)
      af[kk] = *(const bf16x8*)&Xs[(mt*16 + c)*XSTR + kk*32 + g*8];
    f32x4 a0 = {0.f,0.f,0.f,0.f}, a1 = {0.f,0.f,0.f,0.f};
    f32x4 a2 = {0.f,0.f,0.f,0.f}, a3 = {0.f,0.f,0.f,0.f};
    #pragma unroll
    for (int kk=0;kk<4;kk++){
      a0 = __builtin_amdgcn_mfma_f32_16x16x32_bf16(af[kk], bfr[0][kk], a0, 0,0,0);
      a1 = __builtin_amdgcn_mfma_f32_16x16x32_bf16(af[kk], bfr[1][kk], a1, 0,0,0);
      a2 = __builtin_amdgcn_mfma_f32_16x16x32_bf16(af[kk], bfr[2][kk], a2, 0,0,0);
      a3 = __builtin_amdgcn_mfma_f32_16x16x32_bf16(af[kk], bfr[3][kk], a3, 0,0,0);
    }
    f32x4 accs[4] = {a0,a1,a2,a3};
    #pragma unroll
    for (int ctj=0;ctj<4;ctj++){
      #pragma unroll
      for (int r=0;r<4;r++){
        float v = accs[ctj][r];
        if (doSig) v = 1.f/(1.f+__expf(-(v + bgv[ctj])));
        dst[(row0 + mt*16 + 4*g + r)*C_ + (ctBase+ctj)*16 + c] = f2bf(v);
      }
    }
  }
}

// ---------------- attention (MFMA): one block per (n, h) -------------------
#define VSTR 264
__global__ __launch_bounds__(256) void attn_kernel(
    const u16* qb, const u16* __restrict__ kb,
    const u16* __restrict__ vb, const u16* __restrict__ gb,
    const float* __restrict__ bias, const float* __restrict__ nbias,
    u16* wab)
{
  __shared__ u16 Vt[32*VSTR];        // V transposed: Vt[d][k], 16896 B
  __shared__ u16 Ps[4][16][VSTR];    // per-wave P tile, 33792 B
  __shared__ float Bs[256];          // bias row, 1024 B

  const int t  = threadIdx.x;
  const int h  = blockIdx.x;
  const int n  = blockIdx.y;
  const int w  = t >> 6;
  const int l  = t & 63;
  const int c  = l & 15;
  const int g  = l >> 4;

  // ---- stage V^T (256 k x 32 d) and bias row ----
  {
    const u16* vsrc = vb + ((size_t)n*N_)*C_ + h*DH_;
    for (int id = t; id < 1024; id += 256){
      int k = id >> 2, ch = id & 3;
      ushort4 a = *(const ushort4*)(vsrc + (size_t)k*C_ + ch*8);
      ushort4 b = *(const ushort4*)(vsrc + (size_t)k*C_ + ch*8 + 4);
      int d0 = ch*8;
      Vt[(d0+0)*VSTR + k] = a.x;  Vt[(d0+1)*VSTR + k] = a.y;
      Vt[(d0+2)*VSTR + k] = a.z;  Vt[(d0+3)*VSTR + k] = a.w;
      Vt[(d0+4)*VSTR + k] = b.x;  Vt[(d0+5)*VSTR + k] = b.y;
      Vt[(d0+6)*VSTR + k] = b.z;  Vt[(d0+7)*VSTR + k] = b.w;
    }
    Bs[t] = bias[(size_t)n*N_ + t];
  }
  __syncthreads();

  // ---- hoist K B-frags ----
  bf16x8 kf[16];
  {
    const u16* kbase = kb + ((size_t)(n*N_ + c))*C_ + h*DH_ + g*8;
    #pragma unroll
    for (int kt=0;kt<16;kt++)
      kf[kt] = *(const bf16x8*)(kbase + (size_t)kt*16*C_);
  }

  const float* nbp = nbias + (size_t)h*N_*N_;

  for (int qt=0; qt<4; qt++){
    const int q0 = w*64 + qt*16;

    bf16x8 af = *(const bf16x8*)(qb + ((size_t)(n*N_ + q0 + c))*C_ + h*DH_ + g*8);

    const float* nbrow = nbp + (size_t)(q0 + 4*g)*N_ + c;
    f32x4 acc[16];
    #pragma unroll
    for (int kt=0;kt<16;kt++){
      const float bsv = Bs[kt*16 + c];
      f32x4 ci;
      #pragma unroll
      for (int r=0;r<4;r++) ci[r] = bsv + nbrow[(size_t)r*N_ + kt*16];
      acc[kt] = __builtin_amdgcn_mfma_f32_16x16x32_bf16(af, kf[kt], ci, 0, 0, 0);
    }

    // softmax across k
    float inv[4];
    #pragma unroll
    for (int r=0;r<4;r++){
      float m = acc[0][r];
      #pragma unroll
      for (int kt=1;kt<16;kt++) m = fmaxf(m, acc[kt][r]);
      #pragma unroll
      for (int s=8;s>=1;s>>=1) m = fmaxf(m, __shfl_xor(m, s));
      float sum = 0.f;
      #pragma unroll
      for (int kt=0;kt<16;kt++){
        float p = __expf(acc[kt][r] - m);
        acc[kt][r] = p;
        sum += p;
      }
      #pragma unroll
      for (int s=8;s>=1;s>>=1) sum += __shfl_xor(sum, s);
      inv[r] = 1.f/sum;
    }

    // write P as bf16 to per-wave LDS
    #pragma unroll
    for (int kt=0;kt<16;kt++){
      #pragma unroll
      for (int r=0;r<4;r++)
        Ps[w][4*g + r][kt*16 + c] = f2bf(acc[kt][r]);
    }

    // PV
    f32x4 o0 = {0.f,0.f,0.f,0.f}, o1 = {0.f,0.f,0.f,0.f};
    #pragma unroll
    for (int s=0;s<8;s++){
      bf16x8 pa = *(const bf16x8*)&Ps[w][c][s*32 + g*8];
      bf16x8 v0 = *(const bf16x8*)&Vt[(size_t)c*VSTR      + s*32 + g*8];
      bf16x8 v1 = *(const bf16x8*)&Vt[(size_t)(16+c)*VSTR + s*32 + g*8];
      o0 = __builtin_amdgcn_mfma_f32_16x16x32_bf16(pa, v0, o0, 0, 0, 0);
      o1 = __builtin_amdgcn_mfma_f32_16x16x32_bf16(pa, v1, o1, 0, 0, 0);
    }

    // normalize, gate, store
    #pragma unroll
    for (int r=0;r<4;r++){
      size_t row = (size_t)n*N_ + q0 + 4*g + r;
      float gv0 = bf2f(gb[row*C_ + h*DH_ + c]);
      float gv1 = bf2f(gb[row*C_ + h*DH_ + 16 + c]);
      wab[row*C_ + h*DH_ + c]      = f2bf(o0[r]*inv[r]*gv0);
      wab[row*C_ + h*DH_ + 16 + c] = f2bf(o1[r]*inv[r]*gv1);
    }
  }
}

// ---------------- output projection (MFMA) ---------------------------------
// grid 512; block handles 128 rows; wo staged bf16 in LDS.
#define WSTR 136
__global__ __launch_bounds__(256, 2) void outproj_kernel(
    const u16* __restrict__ wab, const float* __restrict__ wo,
    const float* __restrict__ bo, float* __restrict__ out)
{
  __shared__ u16 Wos[128*WSTR];   // 34816 B
  const int t = threadIdx.x;
  const size_t row0 = (size_t)blockIdx.x * 128;

  #pragma unroll
  for (int p=0;p<8;p++){
    int id = t + p*256;
    int r = id >> 4, c0 = (id & 15)*8;
    const float* s = wo + r*C_ + c0;
    float4 a = *(const float4*)s;
    float4 b = *(const float4*)(s+4);
    u16* d = &Wos[r*WSTR + c0];
    d[0]=f2bf(a.x); d[1]=f2bf(a.y); d[2]=f2bf(a.z); d[3]=f2bf(a.w);
    d[4]=f2bf(b.x); d[5]=f2bf(b.y); d[6]=f2bf(b.z); d[7]=f2bf(b.w);
  }

  const int w = t >> 6, l = t & 63, c = l & 15, g = l >> 4;

  // A-frags: wave w owns rows [row0 + 32w, +32)
  bf16x8 af[2][4];
  #pragma unroll
  for (int mt=0;mt<2;mt++){
    const u16* ap = wab + (row0 + w*32 + mt*16 + c)*C_ + g*8;
    #pragma unroll
    for (int kk=0;kk<4;kk++)
      af[mt][kk] = *(const bf16x8*)(ap + kk*32);
  }
  __syncthreads();

  for (int ct=0;ct<8;ct++){
    bf16x8 bfr[4];
    #pragma unroll
    for (int kk=0;kk<4;kk++)
      bfr[kk] = *(const bf16x8*)&Wos[(ct*16 + c)*WSTR + kk*32 + g*8];
    f32x4 acc0 = {0.f,0.f,0.f,0.f}, acc1 = {0.f,0.f,0.f,0.f};
    #pragma unroll
    for (int kk=0;kk<4;kk++){
      acc0 = __builtin_amdgcn_mfma_f32_16x16x32_bf16(af[0][kk], bfr[kk], acc0, 0,0,0);
      acc1 = __builtin_amdgcn_mfma_f32_16x16x32_bf16(af[1][kk], bfr[kk], acc1, 0,0,0);
    }
    const float bov = bo[ct*16 + c];
    #pragma unroll
    for (int r=0;r<4;r++){
      out[(row0 + w*32 +      4*g + r)*C_ + ct*16 + c] = acc0[r] + bov;
      out[(row0 + w*32 + 16 + 4*g + r)*C_ + ct*16 + c] = acc1[r] + bov;
    }
  }
}

extern "C" void kernel_launch(void* const* d_in, const int* in_sizes, int n_in,
                              void* d_out, int out_size, void* d_ws, size_t ws_size,
                              hipStream_t stream) {
  const float* qd   = (const float*)d_in[0];
  const float* md   = (const float*)d_in[1];
  const float* bias = (const float*)d_in[2];
  const float* nb   = (const float*)d_in[3];
  const float* wq   = (const float*)d_in[4];
  const float* wk   = (const float*)d_in[5];
  const float* wv   = (const float*)d_in[6];
  const float* wo   = (const float*)d_in[7];
  const float* bo   = (const float*)d_in[8];
  const float* wg   = (const float*)d_in[9];
  const float* bg   = (const float*)d_in[10];
  float* out = (float*)d_out;

  char* ws = (char*)d_ws;
  const size_t MB16 = (size_t)16*1024*1024;
  u16* qb  = (u16*)(ws);
  u16* kb  = (u16*)(ws + MB16);
  u16* vb  = (u16*)(ws + 2*MB16);
  u16* gb  = (u16*)(ws + 3*MB16);
  u16* wab = qb;                    // in-place reuse (disjoint row/col slices)
  u16* wtb = (u16*)d_out;           // bf16 weights scratch in d_out head;
                                    // consumed by proj before outproj overwrites

  wconv_kernel<<<64, 256, 0, stream>>>(wq, wk, wv, wg, wtb);
  proj_kernel<<<dim3(256, 2), 256, 0, stream>>>(qd, md, wtb, bg, qb, kb, vb, gb);
  attn_kernel<<<dim3(H_, N_), 256, 0, stream>>>(qb, kb, vb, gb, bias, nb, wab);
  outproj_kernel<<<512, 256, 0, stream>>>(wab, wo, bo, out);
}